// Round 8
// baseline (551.697 us; speedup 1.0000x reference)
//
#include <hip/hip_runtime.h>
#include <math.h>

#define BB 128
#define HH 8
#define DD 256
#define MM 8192
#define BH (BB*HH)   // 1024
#define RANK 16

typedef __attribute__((ext_vector_type(8))) short bf16x8;
typedef __attribute__((ext_vector_type(4))) float f32x4;

__device__ inline unsigned short f2bf(float f) {
  unsigned x = __float_as_uint(f);
  unsigned r = x + 0x7FFFu + ((x >> 16) & 1u);
  return (unsigned short)(r >> 16);
}
__device__ inline float bf2f(unsigned short u) {
  return __uint_as_float(((unsigned)u) << 16);
}

// ---------------------------------------------------------------------------
// K1: q[b,h,i] = sum_j probe[h,i,j] * psi[b,j]  (complex)
// ---------------------------------------------------------------------------
__global__ __launch_bounds__(256) void k_q(
    const float* __restrict__ psi, const float* __restrict__ probe_r,
    const float* __restrict__ probe_i, float* __restrict__ qr, float* __restrict__ qi) {
  __shared__ float2 ps0[DD];
  __shared__ float2 ps1[DD];
  int b0 = blockIdx.x * 2;
  int h  = blockIdx.y;
  int i  = threadIdx.x;
  ps0[i] = ((const float2*)psi)[(size_t)b0 * DD + i];
  ps1[i] = ((const float2*)psi)[(size_t)(b0 + 1) * DD + i];
  __syncthreads();
  const float* rr = probe_r + ((size_t)h * DD + i) * DD;
  const float* ri = probe_i + ((size_t)h * DD + i) * DD;
  float a0r = 0.f, a0i = 0.f, a1r = 0.f, a1i = 0.f;
  for (int j = 0; j < DD; j += 4) {
    float4 xr = *(const float4*)(rr + j);
    float4 xi = *(const float4*)(ri + j);
    float2 p0 = ps0[j+0], p1 = ps0[j+1], p2 = ps0[j+2], p3 = ps0[j+3];
    a0r += xr.x*p0.x - xi.x*p0.y;  a0i += xr.x*p0.y + xi.x*p0.x;
    a0r += xr.y*p1.x - xi.y*p1.y;  a0i += xr.y*p1.y + xi.y*p1.x;
    a0r += xr.z*p2.x - xi.z*p2.y;  a0i += xr.z*p2.y + xi.z*p2.x;
    a0r += xr.w*p3.x - xi.w*p3.y;  a0i += xr.w*p3.y + xi.w*p3.x;
    float2 s0 = ps1[j+0], s1 = ps1[j+1], s2 = ps1[j+2], s3 = ps1[j+3];
    a1r += xr.x*s0.x - xi.x*s0.y;  a1i += xr.x*s0.y + xi.x*s0.x;
    a1r += xr.y*s1.x - xi.y*s1.y;  a1i += xr.y*s1.y + xi.y*s1.x;
    a1r += xr.z*s2.x - xi.z*s2.y;  a1i += xr.z*s2.y + xi.z*s2.x;
    a1r += xr.w*s3.x - xi.w*s3.y;  a1i += xr.w*s3.y + xi.w*s3.x;
  }
  size_t o0 = ((size_t)(b0    ) * HH + h) * DD + i;
  size_t o1 = ((size_t)(b0 + 1) * HH + h) * DD + i;
  qr[o0] = a0r; qi[o0] = a0i;
  qr[o1] = a1r; qi[o1] = a1i;
}

// ---------------------------------------------------------------------------
// K2: inv_nrm / fac per row m
// ---------------------------------------------------------------------------
__global__ __launch_bounds__(256) void k_norm(
    const float* __restrict__ u_r, const float* __restrict__ u_i,
    const float* __restrict__ s_logit, float* __restrict__ inv_nrm,
    float* __restrict__ fac) {
  int m = blockIdx.x * 4 + (threadIdx.x >> 6);
  int lane = threadIdx.x & 63;
  const float4* a = (const float4*)(u_r + (size_t)m * DD);
  const float4* b = (const float4*)(u_i + (size_t)m * DD);
  float4 x = a[lane], y = b[lane];
  float s = x.x*x.x + x.y*x.y + x.z*x.z + x.w*x.w
          + y.x*y.x + y.y*y.y + y.z*y.z + y.w*y.w;
  for (int off = 32; off; off >>= 1) s += __shfl_down(s, off);
  if (lane == 0) {
    float inv = 1.0f / sqrtf(fmaxf(s, 1e-8f));
    inv_nrm[m] = inv;
    float sig = 1.0f / (1.0f + expf(-s_logit[m]));
    fac[m] = sig * inv * inv;
  }
}

// ---------------------------------------------------------------------------
// K3a: build A'' (2048 x 512 bf16, hi only).
// row 2bh:   [qr_hi | qi_hi]
// row 2bh+1: [qi_hi | -qr_hi]
// ---------------------------------------------------------------------------
__global__ __launch_bounds__(256) void k_convA(
    const float* __restrict__ qr, const float* __restrict__ qi,
    unsigned short* __restrict__ Ap) {
  int bh = blockIdx.x, d = threadIdx.x;
  float xr = qr[(size_t)bh*DD + d], xi = qi[(size_t)bh*DD + d];
  unsigned short hr = f2bf(xr), hi_ = f2bf(xi);
  unsigned short* r0 = Ap + (size_t)(2*bh) * 512;
  unsigned short* r1 = r0 + 512;
  r0[d] = hr;  r0[256+d] = hi_;
  r1[d] = hi_; r1[256+d] = hr ^ 0x8000u;
}

// ---------------------------------------------------------------------------
// K3b: build B'' (8192 x 512 bf16, hi only): [ur_hi | ui_hi]
// ---------------------------------------------------------------------------
__global__ __launch_bounds__(256) void k_convB(
    const float* __restrict__ u_r, const float* __restrict__ u_i,
    unsigned short* __restrict__ Bp) {
  int m = blockIdx.x, d = threadIdx.x;
  unsigned short* r = Bp + (size_t)m * 512;
  r[d]     = f2bf(u_r[(size_t)m*DD + d]);
  r[256+d] = f2bf(u_i[(size_t)m*DD + d]);
}

// ---------------------------------------------------------------------------
// K4: bf16 MFMA GEMM, K=512 (hi*hi coarse scores; exact rescore fixes the rest).
// Tile 128(A-rows) x 128(m), BK=64, 4 waves (2x2), 4x4 16x16x32 frags/wave.
// ---------------------------------------------------------------------------
__global__ __launch_bounds__(256, 4) void k_gemm(
    const unsigned short* __restrict__ Ap,   // 2048 x 512
    const unsigned short* __restrict__ Bp,   // 8192 x 512
    const float* __restrict__ fac,           // 8192
    unsigned short* __restrict__ sc) {       // 1024 x 8192 (bf16)
  __shared__ __align__(16) unsigned short SMEM[16384];   // 32 KB
  unsigned short* As = SMEM;          // 128 x 64
  unsigned short* Bs = SMEM + 8192;   // 128 x 64
  int tid  = threadIdx.x;
  int lane = tid & 63, wid = tid >> 6;
  int wm = wid >> 1, wn = wid & 1;
  int a_row0 = blockIdx.y * 128;
  int b_row0 = blockIdx.x * 128;

  int st_r0 = tid >> 3;
  int st_kc = tid & 7;
  int st_slot = (st_kc ^ (st_r0 & 7)) * 16;

  int arow = lane & 15;
  int fr_g = lane >> 4;
  int r7   = lane & 7;
  const char* Abase = (const char*)As + (wm*64 + arow) * 128;
  const char* Bbase = (const char*)Bs + (wn*64 + arow) * 128;

  f32x4 acc[4][4];
#pragma unroll
  for (int i = 0; i < 4; ++i)
#pragma unroll
    for (int j = 0; j < 4; ++j) acc[i][j] = (f32x4){0.f,0.f,0.f,0.f};

  int4 ra[4], rb[4];
  {
    const unsigned short* pa = Ap + (size_t)(a_row0 + st_r0)*512 + 8*st_kc;
    const unsigned short* pb = Bp + (size_t)(b_row0 + st_r0)*512 + 8*st_kc;
#pragma unroll
    for (int i = 0; i < 4; ++i) {
      ra[i] = *(const int4*)(pa + (size_t)i*32*512);
      rb[i] = *(const int4*)(pb + (size_t)i*32*512);
    }
  }
  const int NT = 8;    // 512 / 64
  for (int t = 0; t < NT; ++t) {
    __syncthreads();
#pragma unroll
    for (int i = 0; i < 4; ++i) {
      *(int4*)((char*)As + (st_r0 + 32*i)*128 + st_slot) = ra[i];
      *(int4*)((char*)Bs + (st_r0 + 32*i)*128 + st_slot) = rb[i];
    }
    __syncthreads();
    if (t + 1 < NT) {
      int k0 = (t + 1) * 64;
      const unsigned short* pa = Ap + (size_t)(a_row0 + st_r0)*512 + k0 + 8*st_kc;
      const unsigned short* pb = Bp + (size_t)(b_row0 + st_r0)*512 + k0 + 8*st_kc;
#pragma unroll
      for (int i = 0; i < 4; ++i) {
        ra[i] = *(const int4*)(pa + (size_t)i*32*512);
        rb[i] = *(const int4*)(pb + (size_t)i*32*512);
      }
    }
#pragma unroll
    for (int ks = 0; ks < 2; ++ks) {
      int slot = ((ks*4 + fr_g) ^ r7) * 16;
      bf16x8 a[4], b[4];
#pragma unroll
      for (int fm = 0; fm < 4; ++fm) a[fm] = *(const bf16x8*)(Abase + fm*2048 + slot);
#pragma unroll
      for (int fn = 0; fn < 4; ++fn) b[fn] = *(const bf16x8*)(Bbase + fn*2048 + slot);
#pragma unroll
      for (int fm = 0; fm < 4; ++fm)
#pragma unroll
        for (int fn = 0; fn < 4; ++fn)
          acc[fm][fn] = __builtin_amdgcn_mfma_f32_16x16x32_bf16(a[fm], b[fn], acc[fm][fn], 0, 0, 0);
    }
  }
  // ---- epilogue: scores -> LDS (64 x 128, pitch 136) -> coalesced writes ----
  __syncthreads();
  const int LP = 136;
  int lr0 = wm*32 + 2*(lane >> 4);
  int lc0 = wn*64 + (lane & 15);
  float fv[4];
#pragma unroll
  for (int fn = 0; fn < 4; ++fn)
    fv[fn] = fac[blockIdx.x*128 + lc0 + fn*16];
#pragma unroll
  for (int fm = 0; fm < 4; ++fm) {
#pragma unroll
    for (int fn = 0; fn < 4; ++fn) {
      f32x4 c = acc[fm][fn];
      float s0 = fv[fn]*(c.x*c.x + c.y*c.y);
      float s1 = fv[fn]*(c.z*c.z + c.w*c.w);
      SMEM[(lr0 + fm*8    ) * LP + lc0 + fn*16] = f2bf(s0);
      SMEM[(lr0 + fm*8 + 1) * LP + lc0 + fn*16] = f2bf(s1);
    }
  }
  __syncthreads();
  {
    int row = tid >> 2;
    int seg = tid & 3;
    unsigned short* dst = sc + (size_t)(blockIdx.y*64 + row) * MM
                             + blockIdx.x*128 + seg*32;
    const unsigned short* src = SMEM + row*LP + seg*32;
#pragma unroll
    for (int c4 = 0; c4 < 4; ++c4)
      *(int4*)(dst + c4*8) = *(const int4*)(src + c4*8);
  }
}

// ---------------------------------------------------------------------------
// K5: per-(bh, half) top-32 candidates from coarse scores. grid (BH, 2).
// ---------------------------------------------------------------------------
__global__ __launch_bounds__(256) void k_top32(
    const unsigned short* __restrict__ sc, int* __restrict__ cand) {
  __shared__ unsigned long long wtop[128];
  int bh = blockIdx.x, half = blockIdx.y;
  int tid = threadIdx.x, lane = tid & 63, w = tid >> 6;
  const unsigned short* row = sc + (size_t)bh * MM + half*4096;
  unsigned long long v[16];
#pragma unroll
  for (int j = 0; j < 16; ++j) {
    int idx = j*256 + tid;
    unsigned bits = ((unsigned)row[idx]) << 16;
    v[j] = (((unsigned long long)bits) << 32) | (unsigned)(4095 - idx);
  }
  for (int r = 0; r < 32; ++r) {
    unsigned long long bk = v[0]; int bj = 0;
#pragma unroll
    for (int j = 1; j < 16; ++j) if (v[j] > bk) { bk = v[j]; bj = j; }
    unsigned long long mx = bk;
    for (int off = 32; off; off >>= 1) {
      unsigned long long o = __shfl_xor(mx, off);
      if (o > mx) mx = o;
    }
    if (bk == mx && mx != 0ull) {
#pragma unroll
      for (int j = 0; j < 16; ++j) if (j == bj) v[j] = 0ull;
    }
    if (lane == 0) wtop[w*32 + r] = mx;
  }
  __syncthreads();
  if (w == 0) {
    unsigned long long a = wtop[lane], b = wtop[64 + lane];
    for (int r = 0; r < 32; ++r) {
      unsigned long long bk = (a > b) ? a : b;
      int which = (a > b) ? 0 : 1;
      unsigned long long mx = bk;
      for (int off = 32; off; off >>= 1) {
        unsigned long long o = __shfl_xor(mx, off);
        if (o > mx) mx = o;
      }
      if (bk == mx && mx != 0ull) { if (which == 0) a = 0ull; else b = 0ull; }
      if (lane == 0) {
        int idx = 4095 - (int)(mx & 0xFFFFFFFFull);
        cand[bh*64 + half*32 + r] = half*4096 + idx;
      }
    }
  }
}

// ---------------------------------------------------------------------------
// K6: exact fp32 rescore of the 64 candidates; top-16 with lax tie order.
// ---------------------------------------------------------------------------
__global__ __launch_bounds__(256) void k_exact(
    const float* __restrict__ qr, const float* __restrict__ qi,
    const float* __restrict__ u_r, const float* __restrict__ u_i,
    const float* __restrict__ fac, const int* __restrict__ cand,
    float* __restrict__ topv, int* __restrict__ topi) {
  __shared__ float qrs[DD], qis[DD];
  __shared__ unsigned long long keys[64];
  int bh = blockIdx.x, tid = threadIdx.x, lane = tid & 63, w = tid >> 6;
  qrs[tid] = qr[(size_t)bh*DD + tid];
  qis[tid] = qi[(size_t)bh*DD + tid];
  __syncthreads();
  float4 xr = *(const float4*)&qrs[lane*4];
  float4 xi = *(const float4*)&qis[lane*4];
  for (int c = 0; c < 16; ++c) {
    int ci = w*16 + c;
    int m = cand[bh*64 + ci];
    float4 a = *(const float4*)(u_r + (size_t)m*DD + lane*4);
    float4 b = *(const float4*)(u_i + (size_t)m*DD + lane*4);
    float pr = a.x*xr.x + a.y*xr.y + a.z*xr.z + a.w*xr.w
             + b.x*xi.x + b.y*xi.y + b.z*xi.z + b.w*xi.w;
    float pi2 = a.x*xi.x + a.y*xi.y + a.z*xi.z + a.w*xi.w
              - (b.x*xr.x + b.y*xr.y + b.z*xr.z + b.w*xr.w);
    for (int off = 32; off; off >>= 1) {
      pr  += __shfl_down(pr, off);
      pi2 += __shfl_down(pi2, off);
    }
    if (lane == 0) {
      float s = fac[m] * (pr*pr + pi2*pi2);
      keys[ci] = (((unsigned long long)__float_as_uint(s)) << 32)
               | (unsigned)(MM - 1 - m);
    }
  }
  __syncthreads();
  if (w == 0) {
    unsigned long long k = keys[lane];
    for (int r = 0; r < 16; ++r) {
      unsigned long long mx = k;
      for (int off = 32; off; off >>= 1) {
        unsigned long long o = __shfl_xor(mx, off);
        if (o > mx) mx = o;
      }
      if (k == mx && mx != 0ull) k = 0ull;
      if (lane == 0) {
        topv[bh*16 + r] = __uint_as_float((unsigned)(mx >> 32));
        topi[bh*16 + r] = MM - 1 - (int)(mx & 0xFFFFFFFFull);
      }
    }
  }
}

// ---------------------------------------------------------------------------
// K7: Householder QR (clarfg convention) + in-place zung2r + diag + outputs.
// Register-resident: thread d owns row d (Ar/Ai[16] in VGPRs, compile-time
// indexed). Reflector v is thread-local; w-reductions via __shfl_down +
// 4-wave LDS combine (512 B). Replaces the LDS-panel version (50x less LDS
// traffic, 2 barriers/step).
// ---------------------------------------------------------------------------
__global__ __launch_bounds__(256) void k_qr(
    const float* __restrict__ u_r, const float* __restrict__ u_i,
    const float* __restrict__ inv_nrm,
    const float* __restrict__ w_r, const float* __restrict__ w_i,
    const float* __restrict__ topv, const int* __restrict__ topi,
    float* __restrict__ out) {
  __shared__ float redS[4];
  __shared__ float alphaSh[2];
  __shared__ float pw[4][32];      // per-wave partials: 16 complex
  __shared__ float tauSh[16][2];
  __shared__ int   idxs[16];
  __shared__ float fA[16], fW[16];

  int bh = blockIdx.x;
  int tid = threadIdx.x;
  int d = tid;
  int lane = tid & 63, wv = tid >> 6;

  if (tid < 16) {
    int id = topi[bh*16 + tid];
    idxs[tid] = id;
    float w = sqrtf(fmaxf(topv[bh*16 + tid], 0.f));
    fW[tid] = w;
    fA[tid] = w * inv_nrm[id];
  }
  __syncthreads();

  float Ar[16], Ai[16];
#pragma unroll
  for (int j = 0; j < 16; ++j) {
    float f = fA[j];
    size_t base = (size_t)idxs[j] * DD + d;
    Ar[j] = u_r[base] * f;
    Ai[j] = u_i[base] * f;
  }

  // ---- Phase A: factorize (clarfg: beta real, sign = -sign(Re alpha)) ----
  for (int j = 0; j < 16; ++j) {
    float ar = 0.f, ai = 0.f;
#pragma unroll
    for (int c = 0; c < 16; ++c) if (c == j) { ar = Ar[c]; ai = Ai[c]; }
    float xn2 = (d > j) ? (ar*ar + ai*ai) : 0.f;
    for (int off = 32; off; off >>= 1) xn2 += __shfl_down(xn2, off);
    if (lane == 0) redS[wv] = xn2;
    if (d == j) { alphaSh[0] = ar; alphaSh[1] = ai; }
    __syncthreads();                       // B1
    xn2 = redS[0] + redS[1] + redS[2] + redS[3];
    float alr = alphaSh[0], ali = alphaSh[1];
    float taur, taui, scr, sci;
    if (xn2 == 0.f && ali == 0.f) {
      taur = 0.f; taui = 0.f; scr = 0.f; sci = 0.f;
    } else {
      float nrm  = sqrtf(alr*alr + ali*ali + xn2);
      float beta = (alr >= 0.f) ? -nrm : nrm;
      taur = (beta - alr) / beta;
      taui = -ali / beta;
      float dr = alr - beta, di = ali;
      float den = dr*dr + di*di;
      scr = dr / den; sci = -di / den;     // 1/(alpha-beta)
    }
    if (tid == 0) { tauSh[j][0] = taur; tauSh[j][1] = taui; }
    // reflector: v_d = 0 (d<j), 1 (d==j), x_d/(alpha-beta) (d>j); store in col j
    float vr, vi;
    if (d > j)       { vr = ar*scr - ai*sci; vi = ar*sci + ai*scr; }
    else if (d == j) { vr = 1.f; vi = 0.f; }
    else             { vr = 0.f; vi = 0.f; }
#pragma unroll
    for (int c = 0; c < 16; ++c) if (c == j) { Ar[c] = vr; Ai[c] = vi; }
    // w_c = sum_d conj(v_d) * A[d][c],  c > j
#pragma unroll
    for (int c = 0; c < 16; ++c) if (c > j) {
      float lr = vr*Ar[c] + vi*Ai[c];
      float li = vr*Ai[c] - vi*Ar[c];
      for (int off = 32; off; off >>= 1) {
        lr += __shfl_down(lr, off);
        li += __shfl_down(li, off);
      }
      if (lane == 0) { pw[wv][2*c] = lr; pw[wv][2*c+1] = li; }
    }
    __syncthreads();                       // B2
    // A[:,c] -= conj(tau) * v * w_c
    float tr = taur*vr + taui*vi;
    float ti = taur*vi - taui*vr;
#pragma unroll
    for (int c = 0; c < 16; ++c) if (c > j) {
      float wcr = pw[0][2*c] + pw[1][2*c] + pw[2][2*c] + pw[3][2*c];
      float wci = pw[0][2*c+1] + pw[1][2*c+1] + pw[2][2*c+1] + pw[3][2*c+1];
      Ar[c] -= tr*wcr - ti*wci;
      Ai[c] -= tr*wci + ti*wcr;
    }
  }

  // ---- Phase B: zung2r in place (Q overwrites reflectors) ----
  for (int i = 15; i >= 0; --i) {
    __syncthreads();                       // pw handoff barrier
    float taur = tauSh[i][0], taui = tauSh[i][1];
    float vr = 0.f, vi = 0.f;
#pragma unroll
    for (int c = 0; c < 16; ++c) if (c == i) { vr = Ar[c]; vi = Ai[c]; }
#pragma unroll
    for (int c = 0; c < 16; ++c) if (c > i) {
      float lr = vr*Ar[c] + vi*Ai[c];
      float li = vr*Ai[c] - vi*Ar[c];
      for (int off = 32; off; off >>= 1) {
        lr += __shfl_down(lr, off);
        li += __shfl_down(li, off);
      }
      if (lane == 0) { pw[wv][2*c] = lr; pw[wv][2*c+1] = li; }
    }
    __syncthreads();
    float tvr = taur*vr - taui*vi;   // tau * v
    float tvi = taur*vi + taui*vr;
#pragma unroll
    for (int c = 0; c < 16; ++c) if (c > i) {
      float wcr = pw[0][2*c] + pw[1][2*c] + pw[2][2*c] + pw[3][2*c];
      float wci = pw[0][2*c+1] + pw[1][2*c+1] + pw[2][2*c+1] + pw[3][2*c+1];
      Ar[c] -= tvr*wcr - tvi*wci;
      Ai[c] -= tvr*wci + tvi*wcr;
    }
    // column i of Q = e_i - tau*v
    float er = (d == i) ? 1.f : 0.f;
#pragma unroll
    for (int c = 0; c < 16; ++c) if (c == i) { Ar[c] = er - tvr; Ai[c] = -tvi; }
  }

  // ---- diag[r] = sum_d conj(Q[d,r]) * w_row[idx_r][d]  (x fW[r] after) ----
  __syncthreads();
#pragma unroll
  for (int r = 0; r < 16; ++r) {
    size_t base = (size_t)idxs[r] * DD + d;
    float wr2 = w_r[base], wi2 = w_i[base];
    float lr = Ar[r]*wr2 + Ai[r]*wi2;
    float li = Ar[r]*wi2 - Ai[r]*wr2;
    for (int off = 32; off; off >>= 1) {
      lr += __shfl_down(lr, off);
      li += __shfl_down(li, off);
    }
    if (lane == 0) { pw[wv][2*r] = lr; pw[wv][2*r+1] = li; }
  }
  __syncthreads();
  float dgR[16], dgI[16];
#pragma unroll
  for (int r = 0; r < 16; ++r) {
    float f = fW[r];
    dgR[r] = (pw[0][2*r] + pw[1][2*r] + pw[2][2*r] + pw[3][2*r]) * f;
    dgI[r] = (pw[0][2*r+1] + pw[1][2*r+1] + pw[2][2*r+1] + pw[3][2*r+1]) * f;
  }

  size_t baseU = ((size_t)bh * DD + d) * 32;
  size_t baseV = (size_t)BH * DD * 32 + baseU;
  float4* oU = (float4*)(out + baseU);
  float4* oV = (float4*)(out + baseV);
#pragma unroll
  for (int r = 0; r < 16; r += 2) {
    float q0r = Ar[r],   q0i = Ai[r];
    float q1r = Ar[r+1], q1i = Ai[r+1];
    oU[r >> 1] = make_float4(q0r, q0i, q1r, q1i);
    float v0r = q0r*dgR[r]   - q0i*dgI[r];
    float v0i = q0r*dgI[r]   + q0i*dgR[r];
    float v1r = q1r*dgR[r+1] - q1i*dgI[r+1];
    float v1i = q1r*dgI[r+1] + q1i*dgR[r+1];
    oV[r >> 1] = make_float4(v0r, v0i, v1r, v1i);
  }
}

// ---------------------------------------------------------------------------
extern "C" void kernel_launch(void* const* d_in, const int* in_sizes, int n_in,
                              void* d_out, int out_size, void* d_ws, size_t ws_size,
                              hipStream_t stream) {
  (void)in_sizes; (void)n_in; (void)out_size; (void)ws_size;
  const float* psi     = (const float*)d_in[0];
  const float* u_r     = (const float*)d_in[1];
  const float* u_i     = (const float*)d_in[2];
  const float* w_r     = (const float*)d_in[3];
  const float* w_i     = (const float*)d_in[4];
  const float* s_logit = (const float*)d_in[5];
  const float* probe_r = (const float*)d_in[6];
  const float* probe_i = (const float*)d_in[7];

  float* ws = (float*)d_ws;
  float*          qr      = ws;                          // 262144
  float*          qi      = ws + 262144;                 // 262144
  float*          inv_nrm = ws + 524288;                 // 8192
  float*          fac     = ws + 532480;                 // 8192
  float*          topv    = ws + 540672;                 // 16384
  int*            topi    = (int*)(ws + 557056);         // 16384
  int*            cand    = (int*)(ws + 573440);         // 65536 ints
  unsigned short* Ap      = (unsigned short*)(ws + 638976);   // 2048*512 bf16 (2 MB)
  unsigned short* Bp      = (unsigned short*)(ws + 1163264);  // 8192*512 bf16 (8 MB)
  unsigned short* sc      = (unsigned short*)(ws + 3260416);  // 1024*8192 bf16 (16 MB)
  float* out = (float*)d_out;

  hipLaunchKernelGGL(k_q,     dim3(BB/2, HH), dim3(256), 0, stream,
                     psi, probe_r, probe_i, qr, qi);
  hipLaunchKernelGGL(k_norm,  dim3(MM/4),     dim3(256), 0, stream,
                     u_r, u_i, s_logit, inv_nrm, fac);
  hipLaunchKernelGGL(k_convA, dim3(BH),       dim3(256), 0, stream, qr, qi, Ap);
  hipLaunchKernelGGL(k_convB, dim3(MM),       dim3(256), 0, stream, u_r, u_i, Bp);
  hipLaunchKernelGGL(k_gemm,  dim3(64, 16),   dim3(256), 0, stream,
                     Ap, Bp, fac, sc);
  hipLaunchKernelGGL(k_top32, dim3(BH, 2),    dim3(256), 0, stream, sc, cand);
  hipLaunchKernelGGL(k_exact, dim3(BH),       dim3(256), 0, stream,
                     qr, qi, u_r, u_i, fac, cand, topv, topi);
  hipLaunchKernelGGL(k_qr,    dim3(BH),       dim3(256), 0, stream,
                     u_r, u_i, inv_nrm, w_r, w_i, topv, topi, out);
}

// Round 10
// 476.987 us; speedup vs baseline: 1.1566x; 1.1566x over previous
//
#include <hip/hip_runtime.h>
#include <math.h>

#define BB 128
#define HH 8
#define DD 256
#define MM 8192
#define BH (BB*HH)   // 1024
#define RANK 16

typedef __attribute__((ext_vector_type(8))) short bf16x8;
typedef __attribute__((ext_vector_type(4))) float f32x4;

__device__ inline unsigned short f2bf(float f) {
  unsigned x = __float_as_uint(f);
  unsigned r = x + 0x7FFFu + ((x >> 16) & 1u);
  return (unsigned short)(r >> 16);
}
__device__ inline float bf2f(unsigned short u) {
  return __uint_as_float(((unsigned)u) << 16);
}

// ---------------------------------------------------------------------------
// K1: q[b,h,i] = sum_j probe[h,i,j] * psi[b,j]  (complex)
// ---------------------------------------------------------------------------
__global__ __launch_bounds__(256) void k_q(
    const float* __restrict__ psi, const float* __restrict__ probe_r,
    const float* __restrict__ probe_i, float* __restrict__ qr, float* __restrict__ qi) {
  __shared__ float2 ps0[DD];
  __shared__ float2 ps1[DD];
  int b0 = blockIdx.x * 2;
  int h  = blockIdx.y;
  int i  = threadIdx.x;
  ps0[i] = ((const float2*)psi)[(size_t)b0 * DD + i];
  ps1[i] = ((const float2*)psi)[(size_t)(b0 + 1) * DD + i];
  __syncthreads();
  const float* rr = probe_r + ((size_t)h * DD + i) * DD;
  const float* ri = probe_i + ((size_t)h * DD + i) * DD;
  float a0r = 0.f, a0i = 0.f, a1r = 0.f, a1i = 0.f;
  for (int j = 0; j < DD; j += 4) {
    float4 xr = *(const float4*)(rr + j);
    float4 xi = *(const float4*)(ri + j);
    float2 p0 = ps0[j+0], p1 = ps0[j+1], p2 = ps0[j+2], p3 = ps0[j+3];
    a0r += xr.x*p0.x - xi.x*p0.y;  a0i += xr.x*p0.y + xi.x*p0.x;
    a0r += xr.y*p1.x - xi.y*p1.y;  a0i += xr.y*p1.y + xi.y*p1.x;
    a0r += xr.z*p2.x - xi.z*p2.y;  a0i += xr.z*p2.y + xi.z*p2.x;
    a0r += xr.w*p3.x - xi.w*p3.y;  a0i += xr.w*p3.y + xi.w*p3.x;
    float2 s0 = ps1[j+0], s1 = ps1[j+1], s2 = ps1[j+2], s3 = ps1[j+3];
    a1r += xr.x*s0.x - xi.x*s0.y;  a1i += xr.x*s0.y + xi.x*s0.x;
    a1r += xr.y*s1.x - xi.y*s1.y;  a1i += xr.y*s1.y + xi.y*s1.x;
    a1r += xr.z*s2.x - xi.z*s2.y;  a1i += xr.z*s2.y + xi.z*s2.x;
    a1r += xr.w*s3.x - xi.w*s3.y;  a1i += xr.w*s3.y + xi.w*s3.x;
  }
  size_t o0 = ((size_t)(b0    ) * HH + h) * DD + i;
  size_t o1 = ((size_t)(b0 + 1) * HH + h) * DD + i;
  qr[o0] = a0r; qi[o0] = a0i;
  qr[o1] = a1r; qi[o1] = a1i;
}

// ---------------------------------------------------------------------------
// K2: inv_nrm / fac per row m
// ---------------------------------------------------------------------------
__global__ __launch_bounds__(256) void k_norm(
    const float* __restrict__ u_r, const float* __restrict__ u_i,
    const float* __restrict__ s_logit, float* __restrict__ inv_nrm,
    float* __restrict__ fac) {
  int m = blockIdx.x * 4 + (threadIdx.x >> 6);
  int lane = threadIdx.x & 63;
  const float4* a = (const float4*)(u_r + (size_t)m * DD);
  const float4* b = (const float4*)(u_i + (size_t)m * DD);
  float4 x = a[lane], y = b[lane];
  float s = x.x*x.x + x.y*x.y + x.z*x.z + x.w*x.w
          + y.x*y.x + y.y*y.y + y.z*y.z + y.w*y.w;
  for (int off = 32; off; off >>= 1) s += __shfl_down(s, off);
  if (lane == 0) {
    float inv = 1.0f / sqrtf(fmaxf(s, 1e-8f));
    inv_nrm[m] = inv;
    float sig = 1.0f / (1.0f + expf(-s_logit[m]));
    fac[m] = sig * inv * inv;
  }
}

// ---------------------------------------------------------------------------
// K3a: build A'' (2048 x 512 bf16, hi only).
// ---------------------------------------------------------------------------
__global__ __launch_bounds__(256) void k_convA(
    const float* __restrict__ qr, const float* __restrict__ qi,
    unsigned short* __restrict__ Ap) {
  int bh = blockIdx.x, d = threadIdx.x;
  float xr = qr[(size_t)bh*DD + d], xi = qi[(size_t)bh*DD + d];
  unsigned short hr = f2bf(xr), hi_ = f2bf(xi);
  unsigned short* r0 = Ap + (size_t)(2*bh) * 512;
  unsigned short* r1 = r0 + 512;
  r0[d] = hr;  r0[256+d] = hi_;
  r1[d] = hi_; r1[256+d] = hr ^ 0x8000u;
}

// ---------------------------------------------------------------------------
// K3b: build B'' (8192 x 512 bf16, hi only): [ur_hi | ui_hi]
// ---------------------------------------------------------------------------
__global__ __launch_bounds__(256) void k_convB(
    const float* __restrict__ u_r, const float* __restrict__ u_i,
    unsigned short* __restrict__ Bp) {
  int m = blockIdx.x, d = threadIdx.x;
  unsigned short* r = Bp + (size_t)m * 512;
  r[d]     = f2bf(u_r[(size_t)m*DD + d]);
  r[256+d] = f2bf(u_i[(size_t)m*DD + d]);
}

// ---------------------------------------------------------------------------
// K4: bf16 MFMA GEMM, K=512 (hi*hi coarse scores; exact rescore fixes the rest).
// ---------------------------------------------------------------------------
__global__ __launch_bounds__(256, 4) void k_gemm(
    const unsigned short* __restrict__ Ap,   // 2048 x 512
    const unsigned short* __restrict__ Bp,   // 8192 x 512
    const float* __restrict__ fac,           // 8192
    unsigned short* __restrict__ sc) {       // 1024 x 8192 (bf16)
  __shared__ __align__(16) unsigned short SMEM[16384];   // 32 KB
  unsigned short* As = SMEM;          // 128 x 64
  unsigned short* Bs = SMEM + 8192;   // 128 x 64
  int tid  = threadIdx.x;
  int lane = tid & 63, wid = tid >> 6;
  int wm = wid >> 1, wn = wid & 1;
  int a_row0 = blockIdx.y * 128;
  int b_row0 = blockIdx.x * 128;

  int st_r0 = tid >> 3;
  int st_kc = tid & 7;
  int st_slot = (st_kc ^ (st_r0 & 7)) * 16;

  int arow = lane & 15;
  int fr_g = lane >> 4;
  int r7   = lane & 7;
  const char* Abase = (const char*)As + (wm*64 + arow) * 128;
  const char* Bbase = (const char*)Bs + (wn*64 + arow) * 128;

  f32x4 acc[4][4];
#pragma unroll
  for (int i = 0; i < 4; ++i)
#pragma unroll
    for (int j = 0; j < 4; ++j) acc[i][j] = (f32x4){0.f,0.f,0.f,0.f};

  int4 ra[4], rb[4];
  {
    const unsigned short* pa = Ap + (size_t)(a_row0 + st_r0)*512 + 8*st_kc;
    const unsigned short* pb = Bp + (size_t)(b_row0 + st_r0)*512 + 8*st_kc;
#pragma unroll
    for (int i = 0; i < 4; ++i) {
      ra[i] = *(const int4*)(pa + (size_t)i*32*512);
      rb[i] = *(const int4*)(pb + (size_t)i*32*512);
    }
  }
  const int NT = 8;    // 512 / 64
  for (int t = 0; t < NT; ++t) {
    __syncthreads();
#pragma unroll
    for (int i = 0; i < 4; ++i) {
      *(int4*)((char*)As + (st_r0 + 32*i)*128 + st_slot) = ra[i];
      *(int4*)((char*)Bs + (st_r0 + 32*i)*128 + st_slot) = rb[i];
    }
    __syncthreads();
    if (t + 1 < NT) {
      int k0 = (t + 1) * 64;
      const unsigned short* pa = Ap + (size_t)(a_row0 + st_r0)*512 + k0 + 8*st_kc;
      const unsigned short* pb = Bp + (size_t)(b_row0 + st_r0)*512 + k0 + 8*st_kc;
#pragma unroll
      for (int i = 0; i < 4; ++i) {
        ra[i] = *(const int4*)(pa + (size_t)i*32*512);
        rb[i] = *(const int4*)(pb + (size_t)i*32*512);
      }
    }
#pragma unroll
    for (int ks = 0; ks < 2; ++ks) {
      int slot = ((ks*4 + fr_g) ^ r7) * 16;
      bf16x8 a[4], b[4];
#pragma unroll
      for (int fm = 0; fm < 4; ++fm) a[fm] = *(const bf16x8*)(Abase + fm*2048 + slot);
#pragma unroll
      for (int fn = 0; fn < 4; ++fn) b[fn] = *(const bf16x8*)(Bbase + fn*2048 + slot);
#pragma unroll
      for (int fm = 0; fm < 4; ++fm)
#pragma unroll
        for (int fn = 0; fn < 4; ++fn)
          acc[fm][fn] = __builtin_amdgcn_mfma_f32_16x16x32_bf16(a[fm], b[fn], acc[fm][fn], 0, 0, 0);
    }
  }
  // ---- epilogue: scores -> LDS (64 x 128, pitch 136) -> coalesced writes ----
  __syncthreads();
  const int LP = 136;
  int lr0 = wm*32 + 2*(lane >> 4);
  int lc0 = wn*64 + (lane & 15);
  float fv[4];
#pragma unroll
  for (int fn = 0; fn < 4; ++fn)
    fv[fn] = fac[blockIdx.x*128 + lc0 + fn*16];
#pragma unroll
  for (int fm = 0; fm < 4; ++fm) {
#pragma unroll
    for (int fn = 0; fn < 4; ++fn) {
      f32x4 c = acc[fm][fn];
      float s0 = fv[fn]*(c.x*c.x + c.y*c.y);
      float s1 = fv[fn]*(c.z*c.z + c.w*c.w);
      SMEM[(lr0 + fm*8    ) * LP + lc0 + fn*16] = f2bf(s0);
      SMEM[(lr0 + fm*8 + 1) * LP + lc0 + fn*16] = f2bf(s1);
    }
  }
  __syncthreads();
  {
    int row = tid >> 2;
    int seg = tid & 3;
    unsigned short* dst = sc + (size_t)(blockIdx.y*64 + row) * MM
                             + blockIdx.x*128 + seg*32;
    const unsigned short* src = SMEM + row*LP + seg*32;
#pragma unroll
    for (int c4 = 0; c4 < 4; ++c4)
      *(int4*)(dst + c4*8) = *(const int4*)(src + c4*8);
  }
}

// ---------------------------------------------------------------------------
// K5: per-(bh, half) top-32 candidates from coarse scores. grid (BH, 2).
// ---------------------------------------------------------------------------
__global__ __launch_bounds__(256) void k_top32(
    const unsigned short* __restrict__ sc, int* __restrict__ cand) {
  __shared__ unsigned long long wtop[128];
  int bh = blockIdx.x, half = blockIdx.y;
  int tid = threadIdx.x, lane = tid & 63, w = tid >> 6;
  const unsigned short* row = sc + (size_t)bh * MM + half*4096;
  unsigned long long v[16];
#pragma unroll
  for (int j = 0; j < 16; ++j) {
    int idx = j*256 + tid;
    unsigned bits = ((unsigned)row[idx]) << 16;
    v[j] = (((unsigned long long)bits) << 32) | (unsigned)(4095 - idx);
  }
  for (int r = 0; r < 32; ++r) {
    unsigned long long bk = v[0]; int bj = 0;
#pragma unroll
    for (int j = 1; j < 16; ++j) if (v[j] > bk) { bk = v[j]; bj = j; }
    unsigned long long mx = bk;
    for (int off = 32; off; off >>= 1) {
      unsigned long long o = __shfl_xor(mx, off);
      if (o > mx) mx = o;
    }
    if (bk == mx && mx != 0ull) {
#pragma unroll
      for (int j = 0; j < 16; ++j) if (j == bj) v[j] = 0ull;
    }
    if (lane == 0) wtop[w*32 + r] = mx;
  }
  __syncthreads();
  if (w == 0) {
    unsigned long long a = wtop[lane], b = wtop[64 + lane];
    for (int r = 0; r < 32; ++r) {
      unsigned long long bk = (a > b) ? a : b;
      int which = (a > b) ? 0 : 1;
      unsigned long long mx = bk;
      for (int off = 32; off; off >>= 1) {
        unsigned long long o = __shfl_xor(mx, off);
        if (o > mx) mx = o;
      }
      if (bk == mx && mx != 0ull) { if (which == 0) a = 0ull; else b = 0ull; }
      if (lane == 0) {
        int idx = 4095 - (int)(mx & 0xFFFFFFFFull);
        cand[bh*64 + half*32 + r] = half*4096 + idx;
      }
    }
  }
}

// ---------------------------------------------------------------------------
// K6: exact fp32 rescore of the 64 candidates; top-16 with lax tie order.
// ---------------------------------------------------------------------------
__global__ __launch_bounds__(256) void k_exact(
    const float* __restrict__ qr, const float* __restrict__ qi,
    const float* __restrict__ u_r, const float* __restrict__ u_i,
    const float* __restrict__ fac, const int* __restrict__ cand,
    float* __restrict__ topv, int* __restrict__ topi) {
  __shared__ float qrs[DD], qis[DD];
  __shared__ unsigned long long keys[64];
  int bh = blockIdx.x, tid = threadIdx.x, lane = tid & 63, w = tid >> 6;
  qrs[tid] = qr[(size_t)bh*DD + tid];
  qis[tid] = qi[(size_t)bh*DD + tid];
  __syncthreads();
  float4 xr = *(const float4*)&qrs[lane*4];
  float4 xi = *(const float4*)&qis[lane*4];
  for (int c = 0; c < 16; ++c) {
    int ci = w*16 + c;
    int m = cand[bh*64 + ci];
    float4 a = *(const float4*)(u_r + (size_t)m*DD + lane*4);
    float4 b = *(const float4*)(u_i + (size_t)m*DD + lane*4);
    float pr = a.x*xr.x + a.y*xr.y + a.z*xr.z + a.w*xr.w
             + b.x*xi.x + b.y*xi.y + b.z*xi.z + b.w*xi.w;
    float pi2 = a.x*xi.x + a.y*xi.y + a.z*xi.z + a.w*xi.w
              - (b.x*xr.x + b.y*xr.y + b.z*xr.z + b.w*xr.w);
    for (int off = 32; off; off >>= 1) {
      pr  += __shfl_down(pr, off);
      pi2 += __shfl_down(pi2, off);
    }
    if (lane == 0) {
      float s = fac[m] * (pr*pr + pi2*pi2);
      keys[ci] = (((unsigned long long)__float_as_uint(s)) << 32)
               | (unsigned)(MM - 1 - m);
    }
  }
  __syncthreads();
  if (w == 0) {
    unsigned long long k = keys[lane];
    for (int r = 0; r < 16; ++r) {
      unsigned long long mx = k;
      for (int off = 32; off; off >>= 1) {
        unsigned long long o = __shfl_xor(mx, off);
        if (o > mx) mx = o;
      }
      if (k == mx && mx != 0ull) k = 0ull;
      if (lane == 0) {
        topv[bh*16 + r] = __uint_as_float((unsigned)(mx >> 32));
        topi[bh*16 + r] = MM - 1 - (int)(mx & 0xFFFFFFFFull);
      }
    }
  }
}

// ---------------------------------------------------------------------------
// K7: Householder QR (clarfg) + in-place zung2r + diag + outputs.
// ONE WAVE per (b,h): lane l owns rows {l, l+64, l+128, l+192} in VGPRs
// (Ar/Ai[4][16], compile-time indexed). Reductions = 4-row local fold +
// one 6-step __shfl_xor butterfly (wave-uniform c>j guard). No barriers;
// taus pass through 128 B LDS within the wave.
// ---------------------------------------------------------------------------
__global__ __launch_bounds__(64) void k_qr(
    const float* __restrict__ u_r, const float* __restrict__ u_i,
    const float* __restrict__ inv_nrm,
    const float* __restrict__ w_r, const float* __restrict__ w_i,
    const float* __restrict__ topv, const int* __restrict__ topi,
    float* __restrict__ out) {
  __shared__ float tauS[32];
  int bh = blockIdx.x;
  int l  = threadIdx.x;          // 0..63; rows d = l + 64k

  int   idxs[16];
  float fW[16];
  float Ar[4][16], Ai[4][16];
#pragma unroll
  for (int j = 0; j < 16; ++j) {
    int id = topi[bh*16 + j];
    idxs[j] = id;
    float wv = sqrtf(fmaxf(topv[bh*16 + j], 0.f));
    fW[j] = wv;
    float f = wv * inv_nrm[id];
#pragma unroll
    for (int k = 0; k < 4; ++k) {
      size_t base = (size_t)id * DD + l + 64*k;
      Ar[k][j] = u_r[base] * f;
      Ai[k][j] = u_i[base] * f;
    }
  }

  // ---- Phase A: factorize (clarfg: beta real, sign = -sign(Re alpha)) ----
  for (int j = 0; j < 16; ++j) {
    float cAr[4], cAi[4];
#pragma unroll
    for (int c = 0; c < 16; ++c) if (c == j) {
#pragma unroll
      for (int k = 0; k < 4; ++k) { cAr[k] = Ar[k][c]; cAi[k] = Ai[k][c]; }
    }
    // xn2 = sum_{d>j} |A[d][j]|^2  (chunks k>=1 always have d>=64>j)
    float xn2 = (l > j) ? (cAr[0]*cAr[0] + cAi[0]*cAi[0]) : 0.f;
#pragma unroll
    for (int k = 1; k < 4; ++k) xn2 += cAr[k]*cAr[k] + cAi[k]*cAi[k];
#pragma unroll
    for (int off = 32; off; off >>= 1) xn2 += __shfl_xor(xn2, off);
    float alr = __shfl(cAr[0], j);     // row j lives in chunk 0, lane j
    float ali = __shfl(cAi[0], j);
    float taur, taui, scr, sci;
    if (xn2 == 0.f && ali == 0.f) {
      taur = 0.f; taui = 0.f; scr = 0.f; sci = 0.f;
    } else {
      float nrm  = sqrtf(alr*alr + ali*ali + xn2);
      float beta = (alr >= 0.f) ? -nrm : nrm;
      taur = (beta - alr) / beta;
      taui = -ali / beta;
      float dr = alr - beta, di = ali;
      float den = dr*dr + di*di;
      scr = dr / den; sci = -di / den;   // 1/(alpha-beta)
    }
    if (l == 0) { tauS[2*j] = taur; tauS[2*j+1] = taui; }
    // reflector (v_d = 0 for d<j, 1 at d==j)
    float vr[4], vi[4];
    vr[0] = (l > j) ? (cAr[0]*scr - cAi[0]*sci) : ((l == j) ? 1.f : 0.f);
    vi[0] = (l > j) ? (cAr[0]*sci + cAi[0]*scr) : 0.f;
#pragma unroll
    for (int k = 1; k < 4; ++k) {
      vr[k] = cAr[k]*scr - cAi[k]*sci;
      vi[k] = cAr[k]*sci + cAi[k]*scr;
    }
#pragma unroll
    for (int c = 0; c < 16; ++c) if (c == j) {
#pragma unroll
      for (int k = 0; k < 4; ++k) { Ar[k][c] = vr[k]; Ai[k][c] = vi[k]; }
    }
    float pvr[4], pvi[4];   // conj(tau) * v  (geqrf applies H^H)
#pragma unroll
    for (int k = 0; k < 4; ++k) {
      pvr[k] = taur*vr[k] + taui*vi[k];
      pvi[k] = taur*vi[k] - taui*vr[k];
    }
#pragma unroll
    for (int c = 0; c < 16; ++c) {
      if (c > j) {                        // wave-uniform guard
        float lr = 0.f, li = 0.f;
#pragma unroll
        for (int k = 0; k < 4; ++k) {
          lr += vr[k]*Ar[k][c] + vi[k]*Ai[k][c];
          li += vr[k]*Ai[k][c] - vi[k]*Ar[k][c];
        }
#pragma unroll
        for (int off = 32; off; off >>= 1) {
          lr += __shfl_xor(lr, off);
          li += __shfl_xor(li, off);
        }
#pragma unroll
        for (int k = 0; k < 4; ++k) {
          Ar[k][c] -= pvr[k]*lr - pvi[k]*li;
          Ai[k][c] -= pvr[k]*li + pvi[k]*lr;
        }
      }
    }
  }

  // ---- Phase B: zung2r in place (Q overwrites reflectors) ----
  for (int i = 15; i >= 0; --i) {
    float taur = tauS[2*i], taui = tauS[2*i+1];
    float vr[4], vi[4];
#pragma unroll
    for (int c = 0; c < 16; ++c) if (c == i) {
#pragma unroll
      for (int k = 0; k < 4; ++k) { vr[k] = Ar[k][c]; vi[k] = Ai[k][c]; }
    }
    float pvr[4], pvi[4];   // tau * v  (zung2r applies H)
#pragma unroll
    for (int k = 0; k < 4; ++k) {
      pvr[k] = taur*vr[k] - taui*vi[k];
      pvi[k] = taur*vi[k] + taui*vr[k];
    }
#pragma unroll
    for (int c = 0; c < 16; ++c) {
      if (c > i) {
        float lr = 0.f, li = 0.f;
#pragma unroll
        for (int k = 0; k < 4; ++k) {
          lr += vr[k]*Ar[k][c] + vi[k]*Ai[k][c];
          li += vr[k]*Ai[k][c] - vi[k]*Ar[k][c];
        }
#pragma unroll
        for (int off = 32; off; off >>= 1) {
          lr += __shfl_xor(lr, off);
          li += __shfl_xor(li, off);
        }
#pragma unroll
        for (int k = 0; k < 4; ++k) {
          Ar[k][c] -= pvr[k]*lr - pvi[k]*li;
          Ai[k][c] -= pvr[k]*li + pvi[k]*lr;
        }
      }
    }
    // column i of Q = e_i - tau*v  (v=0 above diag -> zeros automatic)
    float er = (l == i) ? 1.f : 0.f;   // d==i only possible in chunk 0
#pragma unroll
    for (int c = 0; c < 16; ++c) if (c == i) {
      Ar[0][c] = er - pvr[0];  Ai[0][c] = -pvi[0];
#pragma unroll
      for (int k = 1; k < 4; ++k) { Ar[k][c] = -pvr[k]; Ai[k][c] = -pvi[k]; }
    }
  }

  // ---- diag[r] = fW[r] * sum_d conj(Q[d,r]) * w_row[idx_r][d] ----
  float dgR[16], dgI[16];
#pragma unroll
  for (int r = 0; r < 16; ++r) {
    float lr = 0.f, li = 0.f;
#pragma unroll
    for (int k = 0; k < 4; ++k) {
      size_t base = (size_t)idxs[r] * DD + l + 64*k;
      float wr2 = w_r[base], wi2 = w_i[base];
      lr += Ar[k][r]*wr2 + Ai[k][r]*wi2;
      li += Ar[k][r]*wi2 - Ai[k][r]*wr2;
    }
#pragma unroll
    for (int off = 32; off; off >>= 1) {
      lr += __shfl_xor(lr, off);
      li += __shfl_xor(li, off);
    }
    dgR[r] = lr * fW[r];
    dgI[r] = li * fW[r];
  }

  // ---- outputs: rows d = l + 64k ----
#pragma unroll
  for (int k = 0; k < 4; ++k) {
    int d = l + 64*k;
    size_t baseU = ((size_t)bh * DD + d) * 32;
    size_t baseV = (size_t)BH * DD * 32 + baseU;
    float4* oU = (float4*)(out + baseU);
    float4* oV = (float4*)(out + baseV);
#pragma unroll
    for (int r = 0; r < 16; r += 2) {
      float q0r = Ar[k][r],   q0i = Ai[k][r];
      float q1r = Ar[k][r+1], q1i = Ai[k][r+1];
      oU[r >> 1] = make_float4(q0r, q0i, q1r, q1i);
      float v0r = q0r*dgR[r]   - q0i*dgI[r];
      float v0i = q0r*dgI[r]   + q0i*dgR[r];
      float v1r = q1r*dgR[r+1] - q1i*dgI[r+1];
      float v1i = q1r*dgI[r+1] + q1i*dgR[r+1];
      oV[r >> 1] = make_float4(v0r, v0i, v1r, v1i);
    }
  }
}

// ---------------------------------------------------------------------------
extern "C" void kernel_launch(void* const* d_in, const int* in_sizes, int n_in,
                              void* d_out, int out_size, void* d_ws, size_t ws_size,
                              hipStream_t stream) {
  (void)in_sizes; (void)n_in; (void)out_size; (void)ws_size;
  const float* psi     = (const float*)d_in[0];
  const float* u_r     = (const float*)d_in[1];
  const float* u_i     = (const float*)d_in[2];
  const float* w_r     = (const float*)d_in[3];
  const float* w_i     = (const float*)d_in[4];
  const float* s_logit = (const float*)d_in[5];
  const float* probe_r = (const float*)d_in[6];
  const float* probe_i = (const float*)d_in[7];

  float* ws = (float*)d_ws;
  float*          qr      = ws;                          // 262144
  float*          qi      = ws + 262144;                 // 262144
  float*          inv_nrm = ws + 524288;                 // 8192
  float*          fac     = ws + 532480;                 // 8192
  float*          topv    = ws + 540672;                 // 16384
  int*            topi    = (int*)(ws + 557056);         // 16384
  int*            cand    = (int*)(ws + 573440);         // 65536 ints
  unsigned short* Ap      = (unsigned short*)(ws + 638976);   // 2048*512 bf16 (2 MB)
  unsigned short* Bp      = (unsigned short*)(ws + 1163264);  // 8192*512 bf16 (8 MB)
  unsigned short* sc      = (unsigned short*)(ws + 3260416);  // 1024*8192 bf16 (16 MB)
  float* out = (float*)d_out;

  hipLaunchKernelGGL(k_q,     dim3(BB/2, HH), dim3(256), 0, stream,
                     psi, probe_r, probe_i, qr, qi);
  hipLaunchKernelGGL(k_norm,  dim3(MM/4),     dim3(256), 0, stream,
                     u_r, u_i, s_logit, inv_nrm, fac);
  hipLaunchKernelGGL(k_convA, dim3(BH),       dim3(256), 0, stream, qr, qi, Ap);
  hipLaunchKernelGGL(k_convB, dim3(MM),       dim3(256), 0, stream, u_r, u_i, Bp);
  hipLaunchKernelGGL(k_gemm,  dim3(64, 16),   dim3(256), 0, stream,
                     Ap, Bp, fac, sc);
  hipLaunchKernelGGL(k_top32, dim3(BH, 2),    dim3(256), 0, stream, sc, cand);
  hipLaunchKernelGGL(k_exact, dim3(BH),       dim3(256), 0, stream,
                     qr, qi, u_r, u_i, fac, cand, topv, topi);
  hipLaunchKernelGGL(k_qr,    dim3(BH),       dim3(64),  0, stream,
                     u_r, u_i, inv_nrm, w_r, w_i, topv, topi, out);
}